// Round 2
// baseline (2296.357 us; speedup 1.0000x reference)
//
#include <hip/hip_runtime.h>
#include <hip/hip_bf16.h>
#include <stdint.h>

#define DEV static __device__ __forceinline__

constexpr int N_ = 50000;
constexpr int E_ = 1600000;
constexpr int G_ = 256;

typedef __attribute__((ext_vector_type(8))) short short8;
typedef __attribute__((ext_vector_type(4))) float float4v;

DEV uint16_t f2bf(float f){
  uint32_t u = __float_as_uint(f);
  uint32_t r = (u + 0x7fffu + ((u >> 16) & 1u)) >> 16;
  return (uint16_t)r;
}
DEV void unpack2(uint32_t p, float& a, float& b){
  a = __uint_as_float(p << 16);
  b = __uint_as_float(p & 0xffff0000u);
}
DEV uint32_t pack2(float a, float b){
  return (uint32_t)f2bf(a) | ((uint32_t)f2bf(b) << 16);
}

// ---------------- x column stats (48 cols over N rows) ----------------
__global__ __launch_bounds__(256) void k_xstats(const float* __restrict__ x, float* __restrict__ xstats){
  __shared__ float lst[96];
  int t = threadIdx.x;
  if (t < 96) lst[t] = 0.f;
  __syncthreads();
  int gid = blockIdx.x * 256 + t;
  int c4 = (gid % 12) * 4;
  float s[4] = {0,0,0,0}, q[4] = {0,0,0,0};
  const float4v* x4 = (const float4v*)x;
  for (int i = gid; i < N_ * 12; i += 64512){
    float4v v = x4[i];
    #pragma unroll
    for (int j = 0; j < 4; j++){ s[j] += v[j]; q[j] += v[j]*v[j]; }
  }
  #pragma unroll
  for (int j = 0; j < 4; j++){
    atomicAdd(&lst[c4 + j], s[j]);
    atomicAdd(&lst[48 + c4 + j], q[j]);
  }
  __syncthreads();
  if (t < 96) atomicAdd(&xstats[t], lst[t]);
}

__global__ void k_xfin(const float* __restrict__ xstats, const float* __restrict__ g,
                       const float* __restrict__ b, float* __restrict__ sx, float* __restrict__ tx){
  int c = threadIdx.x;
  if (c < 48){
    float m = xstats[c] / (float)N_;
    float v = xstats[48 + c] / (float)N_ - m*m;
    float s = g[c] / sqrtf(v + 1e-5f);
    sx[c] = s; tx[c] = b[c] - m*s;
  }
}

// ---------------- histogram of col ----------------
__global__ __launch_bounds__(256) void k_hist(const int* __restrict__ ei, int* __restrict__ counts){
  int e = blockIdx.x * 256 + threadIdx.x;
  if (e < E_) atomicAdd(&counts[ei[E_ + e]], 1);
}

// ---------------- 1/count ----------------
__global__ __launch_bounds__(256) void k_invc(const int* __restrict__ counts, float* __restrict__ invc){
  int n = blockIdx.x * 256 + threadIdx.x;
  if (n < N_){ int c = counts[n]; invc[n] = (c > 0) ? 1.f/(float)c : 0.f; }
}

// ---------------- exclusive scan of counts (single block) ----------------
__global__ __launch_bounds__(256) void k_scan(const int* __restrict__ counts, int* __restrict__ off, int* __restrict__ cur){
  __shared__ int wsum[4];
  __shared__ int carry_s;
  int t = threadIdx.x, lane = t & 63, w = t >> 6;
  if (t == 0) carry_s = 0;
  __syncthreads();
  for (int base = 0; base < N_; base += 1024){
    int i0 = base + t * 4;
    int v0 = (i0 + 0 < N_) ? counts[i0 + 0] : 0;
    int v1 = (i0 + 1 < N_) ? counts[i0 + 1] : 0;
    int v2 = (i0 + 2 < N_) ? counts[i0 + 2] : 0;
    int v3 = (i0 + 3 < N_) ? counts[i0 + 3] : 0;
    int tsum = v0 + v1 + v2 + v3;
    int xs = tsum;
    for (int d = 1; d < 64; d <<= 1){ int y = __shfl_up(xs, d); if (lane >= d) xs += y; }
    if (lane == 63) wsum[w] = xs;
    __syncthreads();
    int woff = 0;
    for (int k = 0; k < w; k++) woff += wsum[k];
    int excl = xs - tsum + woff + carry_s;
    int e0 = excl, e1 = e0 + v0, e2 = e1 + v1, e3 = e2 + v2;
    if (i0 + 0 < N_){ off[i0+0] = e0; cur[i0+0] = e0; }
    if (i0 + 1 < N_){ off[i0+1] = e1; cur[i0+1] = e1; }
    if (i0 + 2 < N_){ off[i0+2] = e2; cur[i0+2] = e2; }
    if (i0 + 3 < N_){ off[i0+3] = e3; cur[i0+3] = e3; }
    __syncthreads();
    if (t == 0) carry_s += wsum[0] + wsum[1] + wsum[2] + wsum[3];
    __syncthreads();
  }
  if (t == 0) off[N_] = carry_s;
}

// ---------------- counting-sort placement ----------------
__global__ __launch_bounds__(256) void k_place(const int* __restrict__ ei, int* __restrict__ cur,
                                               int* __restrict__ rs, int* __restrict__ cs){
  int e = blockIdx.x * 256 + threadIdx.x;
  if (e < E_){
    int c = ei[E_ + e];
    int p = atomicAdd(&cur[c], 1);
    rs[p] = ei[e];
    cs[p] = c;
  }
}

// ---------------- weight precomputation ----------------
__global__ __launch_bounds__(256) void k_wprep(
    const float* __restrict__ eW2, const float* __restrict__ n1W1,
    const float* __restrict__ n1W2, const float* __restrict__ n2W1,
    const float* __restrict__ n2W2, const float* __restrict__ glW1,
    const float* __restrict__ n1b2, const float* __restrict__ n2b2,
    uint16_t* __restrict__ Mt, float* __restrict__ Wcomb,
    float* __restrict__ M3, float* __restrict__ c1, float* __restrict__ c3){
  int flat = blockIdx.x * 256 + threadIdx.x;
  if (flat < 16384){
    int n = flat & 127, k = flat >> 7;
    float a = 0.f;
    for (int j = 0; j < 128; j++) a += eW2[k*128 + j] * n1W1[(48 + j)*128 + n];
    Mt[n*128 + k] = f2bf(a);
  } else if (flat < 32768){
    int b = flat - 16384;
    int n = b & 127, j = b >> 7;
    float a = 0.f;
    for (int m = 0; m < 128; m++) a += n1W2[j*128 + m] * n2W1[(48 + m)*128 + n];
    Wcomb[(48 + j)*128 + n] = a;
  } else if (flat < 38912){
    int b = flat - 32768;
    int n = b & 127, k = b >> 7;
    Wcomb[k*128 + n] = n2W1[k*128 + n];
  } else if (flat < 55296){
    int b = flat - 38912;
    int n = b & 127, j = b >> 7;
    float a = 0.f;
    for (int m = 0; m < 128; m++) a += n2W2[j*128 + m] * glW1[m*128 + n];
    M3[j*128 + n] = a;
  } else if (flat < 55552){
    int e = flat - 55296;
    if (e < 128){
      float a = 0.f;
      for (int m = 0; m < 128; m++) a += n1b2[m] * n2W1[(48 + m)*128 + e];
      c1[e] = a;
    } else {
      int n = e - 128;
      float a = 0.f;
      for (int m = 0; m < 128; m++) a += n2b2[m] * glW1[m*128 + n];
      c3[n] = a;
    }
  }
}

// ---------------- node GEMM: A,B,C (bf16) ----------------
// AC[n][0..127]=A=xn@eW1_top, AC[n][128..255]=C=xn@n1W1_top, Bn[n]=xn@eW1_bot
__global__ __launch_bounds__(256) void k_nodegemm(
    const float* __restrict__ x, const float* __restrict__ sx, const float* __restrict__ tx,
    const float* __restrict__ eW1, const float* __restrict__ n1W1,
    uint16_t* __restrict__ AC, uint16_t* __restrict__ Bn){
  __shared__ float xT[48][36];
  __shared__ float W[48][192];
  int t = threadIdx.x;
  int n0 = blockIdx.x * 32;
  for (int idx = t; idx < 32*48; idx += 256){
    int r = idx / 48, k = idx % 48;
    int n = n0 + r;
    float v = 0.f;
    if (n < N_) v = x[(size_t)n*48 + k] * sx[k] + tx[k];
    xT[k][r] = v;
  }
  int cg = t & 31, ng = t >> 5;
  for (int p = 0; p < 2; p++){
    __syncthreads();
    for (int idx = t; idx < 48*192; idx += 256){
      int k = idx / 192, jl = idx % 192;
      int j = p*192 + jl;
      float wv;
      if (j < 128)      wv = eW1[k*128 + j];
      else if (j < 256) wv = eW1[(48 + k)*128 + (j - 128)];
      else              wv = n1W1[k*128 + (j - 256)];
      W[k][jl] = wv;
    }
    __syncthreads();
    float acc[4][6] = {{0.f}};
    for (int k = 0; k < 48; k++){
      float4v xv = *(const float4v*)&xT[k][ng*4];
      const float* wr = &W[k][cg*6];
      float w0=wr[0],w1=wr[1],w2=wr[2],w3=wr[3],w4=wr[4],w5=wr[5];
      #pragma unroll
      for (int i = 0; i < 4; i++){
        float xi = xv[i];
        acc[i][0] += xi*w0; acc[i][1] += xi*w1; acc[i][2] += xi*w2;
        acc[i][3] += xi*w3; acc[i][4] += xi*w4; acc[i][5] += xi*w5;
      }
    }
    for (int i = 0; i < 4; i++){
      int n = n0 + ng*4 + i;
      if (n >= N_) continue;
      #pragma unroll
      for (int j = 0; j < 6; j++){
        int jj = p*192 + cg*6 + j;
        uint16_t bv = f2bf(acc[i][j]);
        if (jj < 128)      AC[(size_t)n*256 + jj] = bv;
        else if (jj < 256) Bn[(size_t)n*128 + (jj - 128)] = bv;
        else               AC[(size_t)n*256 + 128 + (jj - 256)] = bv;
      }
    }
  }
}

// ---------------- edge BN stats pass (h1e = A[row]+B[col]) ----------------
__global__ __launch_bounds__(256) void k_estats(const int* __restrict__ row, const int* __restrict__ col,
    const uint16_t* __restrict__ AC, const uint16_t* __restrict__ Bn, float* __restrict__ estR){
  __shared__ float red[4][64][4];
  __shared__ float lst[256];
  int t = threadIdx.x, lane = t & 63, w = t >> 6;
  int wid = blockIdx.x * 4 + w, nw = gridDim.x * 4;
  float s0=0,q0=0,s1=0,q1=0;
  const uint32_t* ACu = (const uint32_t*)AC;
  const uint32_t* Bu  = (const uint32_t*)Bn;
  for (int e = wid; e < E_; e += nw){
    int r = row[e], c = col[e];
    uint32_t pa = ACu[(size_t)r*128 + lane];
    uint32_t pb = Bu[(size_t)c*64 + lane];
    float a0,a1,b0,b1; unpack2(pa,a0,a1); unpack2(pb,b0,b1);
    float h0 = a0 + b0, h1 = a1 + b1;
    s0 += h0; q0 += h0*h0; s1 += h1; q1 += h1*h1;
  }
  red[w][lane][0]=s0; red[w][lane][1]=q0; red[w][lane][2]=s1; red[w][lane][3]=q1;
  __syncthreads();
  if (t < 64){
    float S0=0,Q0=0,S1=0,Q1=0;
    for (int ww = 0; ww < 4; ww++){ S0+=red[ww][t][0]; Q0+=red[ww][t][1]; S1+=red[ww][t][2]; Q1+=red[ww][t][3]; }
    lst[2*t] = S0; lst[2*t+1] = S1; lst[128+2*t] = Q0; lst[128+2*t+1] = Q1;
  }
  __syncthreads();
  atomicAdd(&estR[(blockIdx.x & 63)*256 + t], lst[t]);
}

// ---------------- generic BN finalize (128 cols, replicated stats) ----------------
__global__ void k_bnfin(const float* __restrict__ statsR, int reps, const float* __restrict__ g,
                        const float* __restrict__ be, float* __restrict__ s_out, float* __restrict__ t_out,
                        float inv_n){
  int c = threadIdx.x;
  if (c >= 128) return;
  float sm = 0.f, sq = 0.f;
  for (int r = 0; r < reps; r++){ sm += statsR[r*256 + c]; sq += statsR[r*256 + 128 + c]; }
  float m = sm * inv_n;
  float v = sq * inv_n - m*m;
  float s = g[c] / sqrtf(v + 1e-5f);
  s_out[c] = s;
  t_out[c] = be[c] - m*s;
}

// ---------------- edge MFMA pass ----------------
// mode 0: compute h1n tile = relu_e@M + C[row], accumulate n1 BN stats only.
// mode 1: recompute tile, apply BN(n1)+relu, segment-aggregate into aggf by col.
__global__ __launch_bounds__(256) void k_epass(
    const int* __restrict__ rs, const int* __restrict__ cs,
    const uint16_t* __restrict__ AC, const uint16_t* __restrict__ Bn,
    const uint16_t* __restrict__ Mt, const float* __restrict__ se, const float* __restrict__ te,
    const float* __restrict__ sn1, const float* __restrict__ tn1,
    int mode, float* __restrict__ n1R, float* __restrict__ aggf){
  __shared__ __align__(16) uint16_t bufA[64*136];   // relu tile -> later C tile
  __shared__ __align__(16) uint16_t bufB[128*136];  // Mt -> later h tile (rows 0..63) + segacc (rows 64..127)
  __shared__ float sete[512];                       // se | te | sn1 | tn1
  __shared__ float lst[256];
  __shared__ int scol[64], ssid[64], scolseg[64];
  __shared__ int snseg;
  const int t = threadIdx.x;
  const long i0 = (long)blockIdx.x * 64;
  const int lane = t & 63, w = t >> 6;
  const int m = lane & 15, quad = lane >> 4;

  if (t < 128){ sete[t] = se[t]; sete[128 + t] = te[t]; sete[256 + t] = sn1[t]; sete[384 + t] = tn1[t]; }
  if (mode == 0) lst[t] = 0.f;
  if (t < 64) scol[t] = cs[i0 + t];
  __syncthreads();

  if (mode == 1 && t < 64){
    bool bnd = (t > 0) && (scol[t] != scol[t-1]);
    unsigned long long mask = __ballot(bnd);
    int sid = __popcll(mask << (63 - t));
    ssid[t] = sid;
    if (bnd || t == 0) scolseg[sid] = scol[t];
    if (t == 63) snseg = sid + 1;
  }

  // P0: stage relu_e into bufA
  {
    int e = t >> 2, q = t & 3;
    int r = rs[i0 + e], c = scol[e];
    const uint4* Ap = (const uint4*)((const uint32_t*)AC + (size_t)r*128 + q*16);
    const uint4* Bp = (const uint4*)((const uint32_t*)Bn + (size_t)c*64  + q*16);
    uint4* dst = (uint4*)((uint32_t*)bufA + e*68 + q*16);
    int cb = q*32;
    #pragma unroll
    for (int u = 0; u < 4; u++){
      uint4 va = Ap[u], vb = Bp[u];
      float4v sA = *(const float4v*)&sete[cb + u*8];
      float4v sB = *(const float4v*)&sete[cb + u*8 + 4];
      float4v tA = *(const float4v*)&sete[128 + cb + u*8];
      float4v tB = *(const float4v*)&sete[128 + cb + u*8 + 4];
      float a0,a1,b0,b1; uint4 o;
      unpack2(va.x,a0,a1); unpack2(vb.x,b0,b1);
      o.x = pack2(fmaxf(0.f,(a0+b0)*sA[0]+tA[0]), fmaxf(0.f,(a1+b1)*sA[1]+tA[1]));
      unpack2(va.y,a0,a1); unpack2(vb.y,b0,b1);
      o.y = pack2(fmaxf(0.f,(a0+b0)*sA[2]+tA[2]), fmaxf(0.f,(a1+b1)*sA[3]+tA[3]));
      unpack2(va.z,a0,a1); unpack2(vb.z,b0,b1);
      o.z = pack2(fmaxf(0.f,(a0+b0)*sB[0]+tB[0]), fmaxf(0.f,(a1+b1)*sB[1]+tB[1]));
      unpack2(va.w,a0,a1); unpack2(vb.w,b0,b1);
      o.w = pack2(fmaxf(0.f,(a0+b0)*sB[2]+tB[2]), fmaxf(0.f,(a1+b1)*sB[3]+tB[3]));
      dst[u] = o;
    }
  }
  // P1: stage Mt into bufB
  {
    int n = t >> 1, h = t & 1;
    const uint4* src = (const uint4*)((const uint32_t*)Mt + n*64 + h*32);
    uint4* dst = (uint4*)((uint32_t*)bufB + n*68 + h*32);
    #pragma unroll
    for (int u = 0; u < 8; u++) dst[u] = src[u];
  }
  __syncthreads();

  // P2: MFMA — 16 edges/wave x 128 cols, K=128
  float4v acc[8];
  #pragma unroll
  for (int nt = 0; nt < 8; nt++){ acc[nt][0]=0.f; acc[nt][1]=0.f; acc[nt][2]=0.f; acc[nt][3]=0.f; }
  {
    const uint16_t* aptr = bufA + (w*16 + m)*136 + quad*8;
    const uint16_t* bbase = bufB + m*136 + quad*8;
    #pragma unroll
    for (int ks = 0; ks < 4; ks++){
      short8 af = *(const short8*)(aptr + ks*32);
      #pragma unroll
      for (int nt = 0; nt < 8; nt++){
        short8 bf = *(const short8*)(bbase + nt*16*136 + ks*32);
        acc[nt] = __builtin_amdgcn_mfma_f32_16x16x32_bf16(af, bf, acc[nt], 0, 0, 0);
      }
    }
  }
  __syncthreads();

  // P3: stage C tile into bufA; write acc as bf16 into bufB rows 0..63; zero segacc
  {
    int e = t >> 2, q = t & 3;
    int r = rs[i0 + e];
    const uint4* src = (const uint4*)((const uint32_t*)AC + (size_t)r*128 + 64 + q*16);
    uint4* dst = (uint4*)((uint32_t*)bufA + e*68 + q*16);
    #pragma unroll
    for (int u = 0; u < 4; u++) dst[u] = src[u];
  }
  #pragma unroll
  for (int nt = 0; nt < 8; nt++)
    #pragma unroll
    for (int reg = 0; reg < 4; reg++)
      bufB[(w*16 + quad*4 + reg)*136 + nt*16 + m] = f2bf(acc[nt][reg]);
  if (mode == 1 && snseg <= 32){
    float* segacc = (float*)(bufB + 8704);
    for (int i = t; i < snseg*128; i += 256) segacc[i] = 0.f;
  }
  __syncthreads();

  if (mode == 0){
    // P4a: n1 BN stats over h = acc + C
    int cp = t & 63, eg = t >> 6;
    float ss0=0,qq0=0,ss1=0,qq1=0;
    #pragma unroll
    for (int it = 0; it < 16; it++){
      int e = eg*16 + it;
      uint32_t ph = ((uint32_t*)bufB)[e*68 + cp];
      uint32_t pc = ((uint32_t*)bufA)[e*68 + cp];
      float h0,h1,c0,c1v;
      unpack2(ph,h0,h1); unpack2(pc,c0,c1v);
      float v0 = h0 + c0, v1 = h1 + c1v;
      ss0 += v0; qq0 += v0*v0; ss1 += v1; qq1 += v1*v1;
    }
    atomicAdd(&lst[2*cp], ss0);
    atomicAdd(&lst[2*cp+1], ss1);
    atomicAdd(&lst[128+2*cp], qq0);
    atomicAdd(&lst[128+2*cp+1], qq1);
    __syncthreads();
    atomicAdd(&n1R[(blockIdx.x & 63)*256 + t], lst[t]);
  } else {
    // P4b: BN+relu, segment-aggregate by col
    int cp = t & 63, eg = t >> 6;
    float s0 = sete[256+2*cp], s1 = sete[256+2*cp+1];
    float b0 = sete[384+2*cp], b1 = sete[384+2*cp+1];
    int nseg = snseg;
    bool lp = (nseg <= 32);
    float* segacc = (float*)(bufB + 8704);
    int cursid = ssid[eg*16];
    float r0 = 0.f, r1 = 0.f;
    for (int it = 0; it < 16; it++){
      int e = eg*16 + it;
      uint32_t ph = ((uint32_t*)bufB)[e*68 + cp];
      uint32_t pc = ((uint32_t*)bufA)[e*68 + cp];
      float h0,h1,c0,c1v;
      unpack2(ph,h0,h1); unpack2(pc,c0,c1v);
      float v0 = fmaxf(0.f, (h0+c0)*s0 + b0);
      float v1 = fmaxf(0.f, (h1+c1v)*s1 + b1);
      int sid = ssid[e];
      if (sid != cursid){
        if (lp){ atomicAdd(&segacc[cursid*128 + 2*cp], r0); atomicAdd(&segacc[cursid*128 + 2*cp+1], r1); }
        else { int c = scolseg[cursid];
               atomicAdd(&aggf[(size_t)c*128 + 2*cp], r0); atomicAdd(&aggf[(size_t)c*128 + 2*cp+1], r1); }
        cursid = sid; r0 = 0.f; r1 = 0.f;
      }
      r0 += v0; r1 += v1;
    }
    if (lp){ atomicAdd(&segacc[cursid*128 + 2*cp], r0); atomicAdd(&segacc[cursid*128 + 2*cp+1], r1); }
    else { int c = scolseg[cursid];
           atomicAdd(&aggf[(size_t)c*128 + 2*cp], r0); atomicAdd(&aggf[(size_t)c*128 + 2*cp+1], r1); }
    __syncthreads();
    if (lp){
      for (int idx = t; idx < nseg*64; idx += 256){
        int s = idx >> 6, cpp = idx & 63;
        float v0 = segacc[s*128 + 2*cpp], v1 = segacc[s*128 + 2*cpp+1];
        int c = scolseg[s];
        float* dst = &aggf[(size_t)c*128 + 2*cpp];
        if (s == 0 || s == nseg - 1){ atomicAdd(dst, v0); atomicAdd(dst+1, v1); }
        else { dst[0] = v0; dst[1] = v1; }   // middle col: wholly owned by this block
      }
    }
  }
}

// ---------------- n2 GEMM: h_n2 = [xn | agg]@Wcomb + cond*c1, + stats ----------------
__global__ __launch_bounds__(256) void k_n2(const float* __restrict__ x,
    const float* __restrict__ sx, const float* __restrict__ tx,
    const float* __restrict__ aggf, const float* __restrict__ invc,
    const float* __restrict__ Wc, const float* __restrict__ c1, const int* __restrict__ counts,
    float* __restrict__ hn2, float* __restrict__ n2R){
  __shared__ float xT[44][36];
  __shared__ float wT[44][128];
  __shared__ float lst[256];
  int t = threadIdx.x;
  int n0 = blockIdx.x * 32;
  int cg = t & 31, ng = t >> 5;
  lst[t] = 0.f;
  float acc[4][4] = {{0.f}};
  for (int kc = 0; kc < 176; kc += 44){
    __syncthreads();
    for (int idx = t; idx < 32*44; idx += 256){
      int r = idx / 44, k = idx % 44;
      int n = n0 + r, kk = kc + k;
      float v = 0.f;
      if (n < N_){
        if (kk < 48) v = x[(size_t)n*48 + kk] * sx[kk] + tx[kk];
        else         v = aggf[(size_t)n*128 + (kk - 48)] * invc[n];
      }
      xT[k][r] = v;
    }
    for (int idx = t; idx < 44*128; idx += 256){
      int k = idx >> 7, c = idx & 127;
      wT[k][c] = Wc[(kc + k)*128 + c];
    }
    __syncthreads();
    for (int k = 0; k < 44; k++){
      float4v xv = *(const float4v*)&xT[k][ng*4];
      float4v wv = *(const float4v*)&wT[k][cg*4];
      #pragma unroll
      for (int i = 0; i < 4; i++)
        #pragma unroll
        for (int j = 0; j < 4; j++)
          acc[i][j] += xv[i]*wv[j];
    }
  }
  float csum[4] = {0,0,0,0}, cqs[4] = {0,0,0,0};
  for (int i = 0; i < 4; i++){
    int n = n0 + ng*4 + i;
    if (n >= N_) continue;
    bool ok = counts[n] > 0;
    float4v o;
    #pragma unroll
    for (int j = 0; j < 4; j++){
      float vv = acc[i][j] + (ok ? c1[cg*4 + j] : 0.f);
      o[j] = vv; csum[j] += vv; cqs[j] += vv*vv;
    }
    *(float4v*)&hn2[(size_t)n*128 + cg*4] = o;
  }
  #pragma unroll
  for (int j = 0; j < 4; j++){
    atomicAdd(&lst[cg*4 + j], csum[j]);
    atomicAdd(&lst[128 + cg*4 + j], cqs[j]);
  }
  __syncthreads();
  atomicAdd(&n2R[(blockIdx.x & 63)*256 + t], lst[t]);
}

// ---------------- graph offsets from sorted batch ----------------
__global__ void k_goff(const int* __restrict__ batch, int* __restrict__ goff){
  int g = threadIdx.x;
  int lo = 0, hi = N_;
  while (lo < hi){ int mid = (lo + hi) >> 1; if (batch[mid] < g) lo = mid + 1; else hi = mid; }
  goff[g] = lo;
  if (g == 0) goff[256] = N_;
}

// ---------------- per-graph mean of relu(bn(h_n2)) ----------------
__global__ __launch_bounds__(128) void k_gmean(const float* __restrict__ hn2, const int* __restrict__ goff,
    const float* __restrict__ sn2, const float* __restrict__ tn2, float* __restrict__ gmean){
  int g = blockIdx.x, c = threadIdx.x;
  int b = goff[g], e = goff[g+1];
  float s = sn2[c], tt = tn2[c], a = 0.f;
  for (int r = b; r < e; r++) a += fmaxf(0.f, hn2[(size_t)r*128 + c]*s + tt);
  gmean[g*128 + c] = (e > b) ? a/(float)(e - b) : 0.f;
}

// ---------------- hg = gmean@M3 + cond*c3, gl stats ----------------
__global__ __launch_bounds__(256) void k_hg(const float* __restrict__ gmean, const float* __restrict__ M3,
    const float* __restrict__ c3, const int* __restrict__ goff,
    float* __restrict__ hg, float* __restrict__ gls){
  int idx = blockIdx.x * 256 + threadIdx.x;
  int g = idx >> 7, c = idx & 127;
  float a = 0.f;
  for (int k = 0; k < 128; k++) a += gmean[g*128 + k] * M3[k*128 + c];
  if (goff[g+1] > goff[g]) a += c3[c];
  hg[idx] = a;
  atomicAdd(&gls[c], a);
  atomicAdd(&gls[128 + c], a*a);
}

// ---------------- final output ----------------
__global__ __launch_bounds__(256) void k_out(const float* __restrict__ hg, const float* __restrict__ sgl,
    const float* __restrict__ tgl, const float* __restrict__ glW2, const float* __restrict__ glb2,
    float* __restrict__ out){
  int idx = blockIdx.x * 256 + threadIdx.x;
  int g = idx >> 1, o = idx & 1;
  float a = 0.f;
  for (int c = 0; c < 128; c++){
    float r = fmaxf(0.f, hg[g*128 + c]*sgl[c] + tgl[c]);
    a += r * glW2[c*2 + o];
  }
  out[idx] = a + glb2[o];
}

extern "C" void kernel_launch(void* const* d_in, const int* in_sizes, int n_in,
                              void* d_out, int out_size, void* d_ws, size_t ws_size,
                              hipStream_t stream){
  const float* x     = (const float*)d_in[0];
  const int*   ei    = (const int*)d_in[1];
  const int*   batch = (const int*)d_in[2];
  const float* bn_g  = (const float*)d_in[3];
  const float* bn_b  = (const float*)d_in[4];
  const float* eW1   = (const float*)d_in[5];
  const float* e_g   = (const float*)d_in[7];
  const float* e_be  = (const float*)d_in[8];
  const float* eW2   = (const float*)d_in[9];
  const float* n1W1  = (const float*)d_in[11];
  const float* n1_g  = (const float*)d_in[13];
  const float* n1_be = (const float*)d_in[14];
  const float* n1W2  = (const float*)d_in[15];
  const float* n1b2  = (const float*)d_in[16];
  const float* n2W1  = (const float*)d_in[17];
  const float* n2_g  = (const float*)d_in[19];
  const float* n2_be = (const float*)d_in[20];
  const float* n2W2  = (const float*)d_in[21];
  const float* n2b2  = (const float*)d_in[22];
  const float* glW1  = (const float*)d_in[23];
  const float* gl_g  = (const float*)d_in[25];
  const float* gl_be = (const float*)d_in[26];
  const float* glW2  = (const float*)d_in[27];
  const float* glb2  = (const float*)d_in[28];
  float* out = (float*)d_out;

  char* w = (char*)d_ws;
  size_t off = 0;
  auto take = [&](size_t bytes) -> char* {
    char* p = w + off;
    off = (off + bytes + 511) & ~(size_t)511;
    return p;
  };

  // zeroed zone: xstats(96) | estR(64*256) | n1R(64*256) | n2R(64*256) | gls(256) | counts(N)
  const size_t ZONE_WORDS = 96 + 3*64*256 + 256 + N_;
  float* zone   = (float*)take(ZONE_WORDS * 4);
  float* xstats = zone;
  float* estR   = zone + 96;
  float* n1R    = zone + 96 + 64*256;
  float* n2R    = zone + 96 + 2*64*256;
  float* gls    = zone + 96 + 3*64*256;
  int*   counts = (int*)(zone + 96 + 3*64*256 + 256);

  float* sx = (float*)take(48*4);   float* tx = (float*)take(48*4);
  float* se = (float*)take(128*4);  float* te = (float*)take(128*4);
  float* sn1 = (float*)take(128*4); float* tn1 = (float*)take(128*4);
  float* sn2 = (float*)take(128*4); float* tn2 = (float*)take(128*4);
  float* sgl = (float*)take(128*4); float* tgl = (float*)take(128*4);
  float* c1 = (float*)take(128*4);  float* c3 = (float*)take(128*4);
  float* invc  = (float*)take((size_t)N_*4);
  float* Wcomb = (float*)take(176*128*4);
  float* M3    = (float*)take(128*128*4);
  float* gmean = (float*)take(G_*128*4);
  float* hg    = (float*)take(G_*128*4);
  int* offs = (int*)take((N_+1)*4);
  int* cur  = (int*)take(N_*4);
  int* goff = (int*)take(257*4);
  uint16_t* Mt = (uint16_t*)take(128*128*2);
  uint16_t* AC = (uint16_t*)take((size_t)N_*256*2);
  uint16_t* Bn = (uint16_t*)take((size_t)N_*128*2);
  float* aggf  = (float*)take((size_t)N_*128*4);
  float* hn2   = (float*)take((size_t)N_*128*4);
  int* rs = (int*)take((size_t)E_*4);
  int* cs = (int*)take((size_t)E_*4);

  // Guard: if workspace is too small, skip (clean validation failure, no fault).
  if (off > ws_size) return;

  hipMemsetAsync(zone, 0, ZONE_WORDS*4, stream);
  hipMemsetAsync(aggf, 0, (size_t)N_*128*4, stream);

  hipLaunchKernelGGL(k_xstats, dim3(252), dim3(256), 0, stream, x, xstats);
  hipLaunchKernelGGL(k_hist, dim3((E_+255)/256), dim3(256), 0, stream, ei, counts);
  hipLaunchKernelGGL(k_xfin, dim3(1), dim3(64), 0, stream, xstats, bn_g, bn_b, sx, tx);
  hipLaunchKernelGGL(k_scan, dim3(1), dim3(256), 0, stream, counts, offs, cur);
  hipLaunchKernelGGL(k_place, dim3((E_+255)/256), dim3(256), 0, stream, ei, cur, rs, cs);
  hipLaunchKernelGGL(k_invc, dim3((N_+255)/256), dim3(256), 0, stream, counts, invc);
  hipLaunchKernelGGL(k_wprep, dim3(217), dim3(256), 0, stream,
                     eW2, n1W1, n1W2, n2W1, n2W2, glW1, n1b2, n2b2, Mt, Wcomb, M3, c1, c3);
  hipLaunchKernelGGL(k_nodegemm, dim3((N_+31)/32), dim3(256), 0, stream,
                     x, sx, tx, eW1, n1W1, AC, Bn);
  hipLaunchKernelGGL(k_estats, dim3(1024), dim3(256), 0, stream, rs, cs, AC, Bn, estR);
  hipLaunchKernelGGL(k_bnfin, dim3(1), dim3(128), 0, stream, estR, 64, e_g, e_be, se, te, 1.f/(float)E_);
  hipLaunchKernelGGL(k_epass, dim3(E_/64), dim3(256), 0, stream,
                     rs, cs, AC, Bn, Mt, se, te, se, te, 0, n1R, aggf);
  hipLaunchKernelGGL(k_bnfin, dim3(1), dim3(128), 0, stream, n1R, 64, n1_g, n1_be, sn1, tn1, 1.f/(float)E_);
  hipLaunchKernelGGL(k_epass, dim3(E_/64), dim3(256), 0, stream,
                     rs, cs, AC, Bn, Mt, se, te, sn1, tn1, 1, n1R, aggf);
  hipLaunchKernelGGL(k_n2, dim3((N_+31)/32), dim3(256), 0, stream,
                     x, sx, tx, aggf, invc, Wcomb, c1, counts, hn2, n2R);
  hipLaunchKernelGGL(k_bnfin, dim3(1), dim3(128), 0, stream, n2R, 64, n2_g, n2_be, sn2, tn2, 1.f/(float)N_);
  hipLaunchKernelGGL(k_goff, dim3(1), dim3(256), 0, stream, batch, goff);
  hipLaunchKernelGGL(k_gmean, dim3(256), dim3(128), 0, stream, hn2, goff, sn2, tn2, gmean);
  hipLaunchKernelGGL(k_hg, dim3(128), dim3(256), 0, stream, gmean, M3, c3, goff, hg, gls);
  hipLaunchKernelGGL(k_bnfin, dim3(1), dim3(128), 0, stream, gls, 1, gl_g, gl_be, sgl, tgl, 1.f/(float)G_);
  hipLaunchKernelGGL(k_out, dim3(2), dim3(256), 0, stream, hg, sgl, tgl, glW2, glb2, out);
}

// Round 3
// 1690.735 us; speedup vs baseline: 1.3582x; 1.3582x over previous
//
#include <hip/hip_runtime.h>
#include <hip/hip_bf16.h>
#include <stdint.h>

#define DEV static __device__ __forceinline__

constexpr int N_ = 50000;
constexpr int E_ = 1600000;
constexpr int G_ = 256;

typedef __attribute__((ext_vector_type(8))) short short8;
typedef __attribute__((ext_vector_type(4))) float float4v;

DEV uint16_t f2bf(float f){
  uint32_t u = __float_as_uint(f);
  uint32_t r = (u + 0x7fffu + ((u >> 16) & 1u)) >> 16;
  return (uint16_t)r;
}
DEV void unpack2(uint32_t p, float& a, float& b){
  a = __uint_as_float(p << 16);
  b = __uint_as_float(p & 0xffff0000u);
}
DEV uint32_t pack2(float a, float b){
  return (uint32_t)f2bf(a) | ((uint32_t)f2bf(b) << 16);
}

// ---------------- x column stats (48 cols over N rows) ----------------
__global__ __launch_bounds__(256) void k_xstats(const float* __restrict__ x, float* __restrict__ xstats){
  __shared__ float lst[96];
  int t = threadIdx.x;
  if (t < 96) lst[t] = 0.f;
  __syncthreads();
  int gid = blockIdx.x * 256 + t;
  int c4 = (gid % 12) * 4;
  float s[4] = {0,0,0,0}, q[4] = {0,0,0,0};
  const float4v* x4 = (const float4v*)x;
  for (int i = gid; i < N_ * 12; i += 64512){
    float4v v = x4[i];
    #pragma unroll
    for (int j = 0; j < 4; j++){ s[j] += v[j]; q[j] += v[j]*v[j]; }
  }
  #pragma unroll
  for (int j = 0; j < 4; j++){
    atomicAdd(&lst[c4 + j], s[j]);
    atomicAdd(&lst[48 + c4 + j], q[j]);
  }
  __syncthreads();
  if (t < 96) atomicAdd(&xstats[t], lst[t]);
}

__global__ void k_xfin(const float* __restrict__ xstats, const float* __restrict__ g,
                       const float* __restrict__ b, float* __restrict__ sx, float* __restrict__ tx){
  int c = threadIdx.x;
  if (c < 48){
    float m = xstats[c] / (float)N_;
    float v = xstats[48 + c] / (float)N_ - m*m;
    float s = g[c] / sqrtf(v + 1e-5f);
    sx[c] = s; tx[c] = b[c] - m*s;
  }
}

// ---------------- histogram of col ----------------
__global__ __launch_bounds__(256) void k_hist(const int* __restrict__ ei, int* __restrict__ counts){
  int e = blockIdx.x * 256 + threadIdx.x;
  if (e < E_) atomicAdd(&counts[ei[E_ + e]], 1);
}

// ---------------- 1/count ----------------
__global__ __launch_bounds__(256) void k_invc(const int* __restrict__ counts, float* __restrict__ invc){
  int n = blockIdx.x * 256 + threadIdx.x;
  if (n < N_){ int c = counts[n]; invc[n] = (c > 0) ? 1.f/(float)c : 0.f; }
}

// ---------------- exclusive scan of counts (single block) ----------------
__global__ __launch_bounds__(256) void k_scan(const int* __restrict__ counts, int* __restrict__ off, int* __restrict__ cur){
  __shared__ int wsum[4];
  __shared__ int carry_s;
  int t = threadIdx.x, lane = t & 63, w = t >> 6;
  if (t == 0) carry_s = 0;
  __syncthreads();
  for (int base = 0; base < N_; base += 1024){
    int i0 = base + t * 4;
    int v0 = (i0 + 0 < N_) ? counts[i0 + 0] : 0;
    int v1 = (i0 + 1 < N_) ? counts[i0 + 1] : 0;
    int v2 = (i0 + 2 < N_) ? counts[i0 + 2] : 0;
    int v3 = (i0 + 3 < N_) ? counts[i0 + 3] : 0;
    int tsum = v0 + v1 + v2 + v3;
    int xs = tsum;
    for (int d = 1; d < 64; d <<= 1){ int y = __shfl_up(xs, d); if (lane >= d) xs += y; }
    if (lane == 63) wsum[w] = xs;
    __syncthreads();
    int woff = 0;
    for (int k = 0; k < w; k++) woff += wsum[k];
    int excl = xs - tsum + woff + carry_s;
    int e0 = excl, e1 = e0 + v0, e2 = e1 + v1, e3 = e2 + v2;
    if (i0 + 0 < N_){ off[i0+0] = e0; cur[i0+0] = e0; }
    if (i0 + 1 < N_){ off[i0+1] = e1; cur[i0+1] = e1; }
    if (i0 + 2 < N_){ off[i0+2] = e2; cur[i0+2] = e2; }
    if (i0 + 3 < N_){ off[i0+3] = e3; cur[i0+3] = e3; }
    __syncthreads();
    if (t == 0) carry_s += wsum[0] + wsum[1] + wsum[2] + wsum[3];
    __syncthreads();
  }
  if (t == 0) off[N_] = carry_s;
}

// ---------------- counting-sort placement (packed int2) ----------------
__global__ __launch_bounds__(256) void k_place(const int* __restrict__ ei, int* __restrict__ cur,
                                               int2* __restrict__ rcs){
  int e = blockIdx.x * 256 + threadIdx.x;
  if (e < E_){
    int c = ei[E_ + e];
    int p = atomicAdd(&cur[c], 1);
    rcs[p] = make_int2(ei[e], c);
  }
}

// ---------------- weight precomputation ----------------
__global__ __launch_bounds__(256) void k_wprep(
    const float* __restrict__ eW2, const float* __restrict__ n1W1,
    const float* __restrict__ n1W2, const float* __restrict__ n2W1,
    const float* __restrict__ n2W2, const float* __restrict__ glW1,
    const float* __restrict__ n1b2, const float* __restrict__ n2b2,
    uint16_t* __restrict__ Mt, float* __restrict__ Wcomb,
    float* __restrict__ M3, float* __restrict__ c1, float* __restrict__ c3){
  int flat = blockIdx.x * 256 + threadIdx.x;
  if (flat < 16384){
    int n = flat & 127, k = flat >> 7;
    float a = 0.f;
    for (int j = 0; j < 128; j++) a += eW2[k*128 + j] * n1W1[(48 + j)*128 + n];
    Mt[n*128 + k] = f2bf(a);
  } else if (flat < 32768){
    int b = flat - 16384;
    int n = b & 127, j = b >> 7;
    float a = 0.f;
    for (int m = 0; m < 128; m++) a += n1W2[j*128 + m] * n2W1[(48 + m)*128 + n];
    Wcomb[(48 + j)*128 + n] = a;
  } else if (flat < 38912){
    int b = flat - 32768;
    int n = b & 127, k = b >> 7;
    Wcomb[k*128 + n] = n2W1[k*128 + n];
  } else if (flat < 55296){
    int b = flat - 38912;
    int n = b & 127, j = b >> 7;
    float a = 0.f;
    for (int m = 0; m < 128; m++) a += n2W2[j*128 + m] * glW1[m*128 + n];
    M3[j*128 + n] = a;
  } else if (flat < 55552){
    int e = flat - 55296;
    if (e < 128){
      float a = 0.f;
      for (int m = 0; m < 128; m++) a += n1b2[m] * n2W1[(48 + m)*128 + e];
      c1[e] = a;
    } else {
      int n = e - 128;
      float a = 0.f;
      for (int m = 0; m < 128; m++) a += n2b2[m] * glW1[m*128 + n];
      c3[n] = a;
    }
  }
}

// ---------------- node GEMM v2: A,B,C (bf16), coalesced dword stores ----------------
// seg0: AC[n][0..127]  = xn @ eW1[0:48]
// seg1: Bn[n][0..127]  = xn @ eW1[48:96]
// seg2: AC[n][128..255]= xn @ n1W1[0:48]
__global__ __launch_bounds__(256) void k_nodegemm(
    const float* __restrict__ x, const float* __restrict__ sx, const float* __restrict__ tx,
    const float* __restrict__ eW1, const float* __restrict__ n1W1,
    uint16_t* __restrict__ AC, uint16_t* __restrict__ Bn){
  __shared__ float xT[48][36];   // [k][row], row-pad to 36 for 16B alignment
  __shared__ float W[48][128];
  int t = threadIdx.x;
  int n0 = blockIdx.x * 32;
  // stage x transposed + normalized (coalesced float4 reads)
  for (int idx = t; idx < 384; idx += 256){
    int r = idx / 12, q = idx % 12;
    int n = n0 + r;
    float4v v = {0.f,0.f,0.f,0.f};
    if (n < N_) v = *(const float4v*)&x[(size_t)n*48 + q*4];
    #pragma unroll
    for (int i = 0; i < 4; i++){
      int k = q*4 + i;
      xT[k][r] = v[i] * sx[k] + tx[k];
    }
  }
  int cg = t & 31, ng = t >> 5;
  const float* Wsrc0 = eW1;
  const float* Wsrc1 = eW1 + 48*128;
  const float* Wsrc2 = n1W1;
  for (int seg = 0; seg < 3; seg++){
    const float* Wsrc = (seg == 0) ? Wsrc0 : (seg == 1) ? Wsrc1 : Wsrc2;
    __syncthreads();
    {
      const float4v* src4 = (const float4v*)Wsrc;
      float4v* W4 = (float4v*)W;
      for (int idx = t; idx < 1536; idx += 256) W4[idx] = src4[idx];
    }
    __syncthreads();
    float acc[4][4] = {{0.f}};
    #pragma unroll 4
    for (int k = 0; k < 48; k++){
      float4v xv = *(const float4v*)&xT[k][ng*4];
      float4v wv = *(const float4v*)&W[k][cg*4];
      #pragma unroll
      for (int i = 0; i < 4; i++)
        #pragma unroll
        for (int j = 0; j < 4; j++)
          acc[i][j] += xv[i]*wv[j];
    }
    #pragma unroll
    for (int i = 0; i < 4; i++){
      int n = n0 + ng*4 + i;
      if (n >= N_) continue;
      uint2 pv;
      pv.x = pack2(acc[i][0], acc[i][1]);
      pv.y = pack2(acc[i][2], acc[i][3]);
      if (seg == 0)      *(uint2*)&AC[(size_t)n*256 + cg*4] = pv;
      else if (seg == 1) *(uint2*)&Bn[(size_t)n*128 + cg*4] = pv;
      else               *(uint2*)&AC[(size_t)n*256 + 128 + cg*4] = pv;
    }
  }
}

// ---------------- edge BN stats pass (h1e = A[row]+B[col]) ----------------
__global__ __launch_bounds__(256) void k_estats(const int2* __restrict__ rcs,
    const uint16_t* __restrict__ AC, const uint16_t* __restrict__ Bn, float* __restrict__ estR){
  __shared__ float red[4][64][4];
  __shared__ float lst[256];
  int t = threadIdx.x, lane = t & 63, w = t >> 6;
  int wid = blockIdx.x * 4 + w, nw = gridDim.x * 4;
  float s0=0,q0=0,s1=0,q1=0;
  const uint32_t* ACu = (const uint32_t*)AC;
  const uint32_t* Bu  = (const uint32_t*)Bn;
  for (int e = wid; e < E_; e += nw){
    int2 rc = rcs[e];
    uint32_t pa = ACu[(size_t)rc.x*128 + lane];
    uint32_t pb = Bu[(size_t)rc.y*64 + lane];
    float a0,a1,b0,b1; unpack2(pa,a0,a1); unpack2(pb,b0,b1);
    float h0 = a0 + b0, h1 = a1 + b1;
    s0 += h0; q0 += h0*h0; s1 += h1; q1 += h1*h1;
  }
  red[w][lane][0]=s0; red[w][lane][1]=q0; red[w][lane][2]=s1; red[w][lane][3]=q1;
  __syncthreads();
  if (t < 64){
    float S0=0,Q0=0,S1=0,Q1=0;
    for (int ww = 0; ww < 4; ww++){ S0+=red[ww][t][0]; Q0+=red[ww][t][1]; S1+=red[ww][t][2]; Q1+=red[ww][t][3]; }
    lst[2*t] = S0; lst[2*t+1] = S1; lst[128+2*t] = Q0; lst[128+2*t+1] = Q1;
  }
  __syncthreads();
  atomicAdd(&estR[(blockIdx.x & 63)*256 + t], lst[t]);
}

// ---------------- generic BN finalize (128 cols, replicated stats) ----------------
__global__ void k_bnfin(const float* __restrict__ statsR, int reps, const float* __restrict__ g,
                        const float* __restrict__ be, float* __restrict__ s_out, float* __restrict__ t_out,
                        float inv_n){
  int c = threadIdx.x;
  if (c >= 128) return;
  float sm = 0.f, sq = 0.f;
  for (int r = 0; r < reps; r++){ sm += statsR[r*256 + c]; sq += statsR[r*256 + 128 + c]; }
  float m = sm * inv_n;
  float v = sq * inv_n - m*m;
  float s = g[c] / sqrtf(v + 1e-5f);
  s_out[c] = s;
  t_out[c] = be[c] - m*s;
}

// ---------------- edge MFMA pass ----------------
// mode 0: compute h1n tile = relu_e@M + C[row], accumulate n1 BN stats only.
// mode 1: recompute tile, apply BN(n1)+relu, segment-aggregate into aggf by col.
__global__ __launch_bounds__(256) void k_epass(
    const int2* __restrict__ rcs,
    const uint16_t* __restrict__ AC, const uint16_t* __restrict__ Bn,
    const uint16_t* __restrict__ Mt, const float* __restrict__ se, const float* __restrict__ te,
    const float* __restrict__ sn1, const float* __restrict__ tn1,
    int mode, float* __restrict__ n1R, float* __restrict__ aggf){
  __shared__ __align__(16) uint16_t bufA[64*136];   // relu tile -> later C tile
  __shared__ __align__(16) uint16_t bufB[128*136];  // Mt -> later h tile (rows 0..63) + segacc (rows 64..127)
  __shared__ float sete[512];                       // se | te | sn1 | tn1
  __shared__ float lst[256];
  __shared__ int srow[64], scol[64], ssid[64], scolseg[64];
  __shared__ int snseg;
  const int t = threadIdx.x;
  const long i0 = (long)blockIdx.x * 64;
  const int lane = t & 63, w = t >> 6;
  const int m = lane & 15, quad = lane >> 4;

  if (t < 128){ sete[t] = se[t]; sete[128 + t] = te[t]; sete[256 + t] = sn1[t]; sete[384 + t] = tn1[t]; }
  if (mode == 0) lst[t] = 0.f;
  if (t < 64){ int2 rc = rcs[i0 + t]; srow[t] = rc.x; scol[t] = rc.y; }
  __syncthreads();

  if (mode == 1 && t < 64){
    bool bnd = (t > 0) && (scol[t] != scol[t-1]);
    unsigned long long mask = __ballot(bnd);
    int sid = __popcll(mask << (63 - t));
    ssid[t] = sid;
    if (bnd || t == 0) scolseg[sid] = scol[t];
    if (t == 63) snseg = sid + 1;
  }

  // P0: stage relu_e into bufA
  {
    int e = t >> 2, q = t & 3;
    int r = srow[e], c = scol[e];
    const uint4* Ap = (const uint4*)((const uint32_t*)AC + (size_t)r*128 + q*16);
    const uint4* Bp = (const uint4*)((const uint32_t*)Bn + (size_t)c*64  + q*16);
    uint4* dst = (uint4*)((uint32_t*)bufA + e*68 + q*16);
    int cb = q*32;
    #pragma unroll
    for (int u = 0; u < 4; u++){
      uint4 va = Ap[u], vb = Bp[u];
      float4v sA = *(const float4v*)&sete[cb + u*8];
      float4v sB = *(const float4v*)&sete[cb + u*8 + 4];
      float4v tA = *(const float4v*)&sete[128 + cb + u*8];
      float4v tB = *(const float4v*)&sete[128 + cb + u*8 + 4];
      float a0,a1,b0,b1; uint4 o;
      unpack2(va.x,a0,a1); unpack2(vb.x,b0,b1);
      o.x = pack2(fmaxf(0.f,(a0+b0)*sA[0]+tA[0]), fmaxf(0.f,(a1+b1)*sA[1]+tA[1]));
      unpack2(va.y,a0,a1); unpack2(vb.y,b0,b1);
      o.y = pack2(fmaxf(0.f,(a0+b0)*sA[2]+tA[2]), fmaxf(0.f,(a1+b1)*sA[3]+tA[3]));
      unpack2(va.z,a0,a1); unpack2(vb.z,b0,b1);
      o.z = pack2(fmaxf(0.f,(a0+b0)*sB[0]+tB[0]), fmaxf(0.f,(a1+b1)*sB[1]+tB[1]));
      unpack2(va.w,a0,a1); unpack2(vb.w,b0,b1);
      o.w = pack2(fmaxf(0.f,(a0+b0)*sB[2]+tB[2]), fmaxf(0.f,(a1+b1)*sB[3]+tB[3]));
      dst[u] = o;
    }
  }
  // P1: stage Mt into bufB
  {
    int n = t >> 1, h = t & 1;
    const uint4* src = (const uint4*)((const uint32_t*)Mt + n*64 + h*32);
    uint4* dst = (uint4*)((uint32_t*)bufB + n*68 + h*32);
    #pragma unroll
    for (int u = 0; u < 8; u++) dst[u] = src[u];
  }
  __syncthreads();

  // P2: MFMA — 16 edges/wave x 128 cols, K=128
  float4v acc[8];
  #pragma unroll
  for (int nt = 0; nt < 8; nt++){ acc[nt][0]=0.f; acc[nt][1]=0.f; acc[nt][2]=0.f; acc[nt][3]=0.f; }
  {
    const uint16_t* aptr = bufA + (w*16 + m)*136 + quad*8;
    const uint16_t* bbase = bufB + m*136 + quad*8;
    #pragma unroll
    for (int ks = 0; ks < 4; ks++){
      short8 af = *(const short8*)(aptr + ks*32);
      #pragma unroll
      for (int nt = 0; nt < 8; nt++){
        short8 bf = *(const short8*)(bbase + nt*16*136 + ks*32);
        acc[nt] = __builtin_amdgcn_mfma_f32_16x16x32_bf16(af, bf, acc[nt], 0, 0, 0);
      }
    }
  }
  __syncthreads();

  // P3: stage C tile into bufA; write acc as bf16 into bufB rows 0..63; zero segacc
  {
    int e = t >> 2, q = t & 3;
    int r = srow[e];
    const uint4* src = (const uint4*)((const uint32_t*)AC + (size_t)r*128 + 64 + q*16);
    uint4* dst = (uint4*)((uint32_t*)bufA + e*68 + q*16);
    #pragma unroll
    for (int u = 0; u < 4; u++) dst[u] = src[u];
  }
  #pragma unroll
  for (int nt = 0; nt < 8; nt++)
    #pragma unroll
    for (int reg = 0; reg < 4; reg++)
      bufB[(w*16 + quad*4 + reg)*136 + nt*16 + m] = f2bf(acc[nt][reg]);
  if (mode == 1 && snseg <= 32){
    float* segacc = (float*)(bufB + 8704);
    for (int i = t; i < snseg*128; i += 256) segacc[i] = 0.f;
  }
  __syncthreads();

  if (mode == 0){
    // P4a: n1 BN stats over h = acc + C
    int cp = t & 63, eg = t >> 6;
    float ss0=0,qq0=0,ss1=0,qq1=0;
    #pragma unroll
    for (int it = 0; it < 16; it++){
      int e = eg*16 + it;
      uint32_t ph = ((uint32_t*)bufB)[e*68 + cp];
      uint32_t pc = ((uint32_t*)bufA)[e*68 + cp];
      float h0,h1,c0,c1v;
      unpack2(ph,h0,h1); unpack2(pc,c0,c1v);
      float v0 = h0 + c0, v1 = h1 + c1v;
      ss0 += v0; qq0 += v0*v0; ss1 += v1; qq1 += v1*v1;
    }
    atomicAdd(&lst[2*cp], ss0);
    atomicAdd(&lst[2*cp+1], ss1);
    atomicAdd(&lst[128+2*cp], qq0);
    atomicAdd(&lst[128+2*cp+1], qq1);
    __syncthreads();
    atomicAdd(&n1R[(blockIdx.x & 63)*256 + t], lst[t]);
  } else {
    // P4b: BN+relu, segment-aggregate by col
    int cp = t & 63, eg = t >> 6;
    float s0 = sete[256+2*cp], s1 = sete[256+2*cp+1];
    float b0 = sete[384+2*cp], b1 = sete[384+2*cp+1];
    int nseg = snseg;
    bool lp = (nseg <= 32);
    float* segacc = (float*)(bufB + 8704);
    int cursid = ssid[eg*16];
    float r0 = 0.f, r1 = 0.f;
    for (int it = 0; it < 16; it++){
      int e = eg*16 + it;
      uint32_t ph = ((uint32_t*)bufB)[e*68 + cp];
      uint32_t pc = ((uint32_t*)bufA)[e*68 + cp];
      float h0,h1,c0,c1v;
      unpack2(ph,h0,h1); unpack2(pc,c0,c1v);
      float v0 = fmaxf(0.f, (h0+c0)*s0 + b0);
      float v1 = fmaxf(0.f, (h1+c1v)*s1 + b1);
      int sid = ssid[e];
      if (sid != cursid){
        if (lp){ atomicAdd(&segacc[cursid*128 + 2*cp], r0); atomicAdd(&segacc[cursid*128 + 2*cp+1], r1); }
        else { int c = scolseg[cursid];
               atomicAdd(&aggf[(size_t)c*128 + 2*cp], r0); atomicAdd(&aggf[(size_t)c*128 + 2*cp+1], r1); }
        cursid = sid; r0 = 0.f; r1 = 0.f;
      }
      r0 += v0; r1 += v1;
    }
    if (lp){ atomicAdd(&segacc[cursid*128 + 2*cp], r0); atomicAdd(&segacc[cursid*128 + 2*cp+1], r1); }
    else { int c = scolseg[cursid];
           atomicAdd(&aggf[(size_t)c*128 + 2*cp], r0); atomicAdd(&aggf[(size_t)c*128 + 2*cp+1], r1); }
    __syncthreads();
    if (lp){
      for (int idx = t; idx < nseg*64; idx += 256){
        int s = idx >> 6, cpp = idx & 63;
        float v0 = segacc[s*128 + 2*cpp], v1 = segacc[s*128 + 2*cpp+1];
        int c = scolseg[s];
        float* dst = &aggf[(size_t)c*128 + 2*cpp];
        if (s == 0 || s == nseg - 1){ atomicAdd(dst, v0); atomicAdd(dst+1, v1); }
        else { dst[0] = v0; dst[1] = v1; }   // middle col: wholly owned by this block
      }
    }
  }
}

// ---------------- n2 GEMM: h_n2 = [xn | agg]@Wcomb + cond*c1, + stats ----------------
__global__ __launch_bounds__(256) void k_n2(const float* __restrict__ x,
    const float* __restrict__ sx, const float* __restrict__ tx,
    const float* __restrict__ aggf, const float* __restrict__ invc,
    const float* __restrict__ Wc, const float* __restrict__ c1, const int* __restrict__ counts,
    float* __restrict__ hn2, float* __restrict__ n2R){
  __shared__ float xT[44][36];
  __shared__ float wT[44][128];
  __shared__ float lst[256];
  int t = threadIdx.x;
  int n0 = blockIdx.x * 32;
  int cg = t & 31, ng = t >> 5;
  lst[t] = 0.f;
  float acc[4][4] = {{0.f}};
  for (int kc = 0; kc < 176; kc += 44){
    __syncthreads();
    for (int idx = t; idx < 32*44; idx += 256){
      int r = idx / 44, k = idx % 44;
      int n = n0 + r, kk = kc + k;
      float v = 0.f;
      if (n < N_){
        if (kk < 48) v = x[(size_t)n*48 + kk] * sx[kk] + tx[kk];
        else         v = aggf[(size_t)n*128 + (kk - 48)] * invc[n];
      }
      xT[k][r] = v;
    }
    for (int idx = t; idx < 44*128; idx += 256){
      int k = idx >> 7, c = idx & 127;
      wT[k][c] = Wc[(kc + k)*128 + c];
    }
    __syncthreads();
    for (int k = 0; k < 44; k++){
      float4v xv = *(const float4v*)&xT[k][ng*4];
      float4v wv = *(const float4v*)&wT[k][cg*4];
      #pragma unroll
      for (int i = 0; i < 4; i++)
        #pragma unroll
        for (int j = 0; j < 4; j++)
          acc[i][j] += xv[i]*wv[j];
    }
  }
  float csum[4] = {0,0,0,0}, cqs[4] = {0,0,0,0};
  for (int i = 0; i < 4; i++){
    int n = n0 + ng*4 + i;
    if (n >= N_) continue;
    bool ok = counts[n] > 0;
    float4v o;
    #pragma unroll
    for (int j = 0; j < 4; j++){
      float vv = acc[i][j] + (ok ? c1[cg*4 + j] : 0.f);
      o[j] = vv; csum[j] += vv; cqs[j] += vv*vv;
    }
    *(float4v*)&hn2[(size_t)n*128 + cg*4] = o;
  }
  #pragma unroll
  for (int j = 0; j < 4; j++){
    atomicAdd(&lst[cg*4 + j], csum[j]);
    atomicAdd(&lst[128 + cg*4 + j], cqs[j]);
  }
  __syncthreads();
  atomicAdd(&n2R[(blockIdx.x & 63)*256 + t], lst[t]);
}

// ---------------- graph offsets from sorted batch ----------------
__global__ void k_goff(const int* __restrict__ batch, int* __restrict__ goff){
  int g = threadIdx.x;
  int lo = 0, hi = N_;
  while (lo < hi){ int mid = (lo + hi) >> 1; if (batch[mid] < g) lo = mid + 1; else hi = mid; }
  goff[g] = lo;
  if (g == 0) goff[256] = N_;
}

// ---------------- per-graph mean of relu(bn(h_n2)) ----------------
__global__ __launch_bounds__(128) void k_gmean(const float* __restrict__ hn2, const int* __restrict__ goff,
    const float* __restrict__ sn2, const float* __restrict__ tn2, float* __restrict__ gmean){
  int g = blockIdx.x, c = threadIdx.x;
  int b = goff[g], e = goff[g+1];
  float s = sn2[c], tt = tn2[c], a = 0.f;
  for (int r = b; r < e; r++) a += fmaxf(0.f, hn2[(size_t)r*128 + c]*s + tt);
  gmean[g*128 + c] = (e > b) ? a/(float)(e - b) : 0.f;
}

// ---------------- hg = gmean@M3 + cond*c3, gl stats ----------------
__global__ __launch_bounds__(256) void k_hg(const float* __restrict__ gmean, const float* __restrict__ M3,
    const float* __restrict__ c3, const int* __restrict__ goff,
    float* __restrict__ hg, float* __restrict__ gls){
  int idx = blockIdx.x * 256 + threadIdx.x;
  int g = idx >> 7, c = idx & 127;
  float a = 0.f;
  for (int k = 0; k < 128; k++) a += gmean[g*128 + k] * M3[k*128 + c];
  if (goff[g+1] > goff[g]) a += c3[c];
  hg[idx] = a;
  atomicAdd(&gls[c], a);
  atomicAdd(&gls[128 + c], a*a);
}

// ---------------- final output ----------------
__global__ __launch_bounds__(256) void k_out(const float* __restrict__ hg, const float* __restrict__ sgl,
    const float* __restrict__ tgl, const float* __restrict__ glW2, const float* __restrict__ glb2,
    float* __restrict__ out){
  int idx = blockIdx.x * 256 + threadIdx.x;
  int g = idx >> 1, o = idx & 1;
  float a = 0.f;
  for (int c = 0; c < 128; c++){
    float r = fmaxf(0.f, hg[g*128 + c]*sgl[c] + tgl[c]);
    a += r * glW2[c*2 + o];
  }
  out[idx] = a + glb2[o];
}

extern "C" void kernel_launch(void* const* d_in, const int* in_sizes, int n_in,
                              void* d_out, int out_size, void* d_ws, size_t ws_size,
                              hipStream_t stream){
  const float* x     = (const float*)d_in[0];
  const int*   ei    = (const int*)d_in[1];
  const int*   batch = (const int*)d_in[2];
  const float* bn_g  = (const float*)d_in[3];
  const float* bn_b  = (const float*)d_in[4];
  const float* eW1   = (const float*)d_in[5];
  const float* e_g   = (const float*)d_in[7];
  const float* e_be  = (const float*)d_in[8];
  const float* eW2   = (const float*)d_in[9];
  const float* n1W1  = (const float*)d_in[11];
  const float* n1_g  = (const float*)d_in[13];
  const float* n1_be = (const float*)d_in[14];
  const float* n1W2  = (const float*)d_in[15];
  const float* n1b2  = (const float*)d_in[16];
  const float* n2W1  = (const float*)d_in[17];
  const float* n2_g  = (const float*)d_in[19];
  const float* n2_be = (const float*)d_in[20];
  const float* n2W2  = (const float*)d_in[21];
  const float* n2b2  = (const float*)d_in[22];
  const float* glW1  = (const float*)d_in[23];
  const float* gl_g  = (const float*)d_in[25];
  const float* gl_be = (const float*)d_in[26];
  const float* glW2  = (const float*)d_in[27];
  const float* glb2  = (const float*)d_in[28];
  float* out = (float*)d_out;

  char* w = (char*)d_ws;
  size_t off = 0;
  auto take = [&](size_t bytes) -> char* {
    char* p = w + off;
    off = (off + bytes + 511) & ~(size_t)511;
    return p;
  };

  // zeroed zone: xstats(96) | estR(64*256) | n1R(64*256) | n2R(64*256) | gls(256) | counts(N)
  const size_t ZONE_WORDS = 96 + 3*64*256 + 256 + N_;
  float* zone   = (float*)take(ZONE_WORDS * 4);
  float* xstats = zone;
  float* estR   = zone + 96;
  float* n1R    = zone + 96 + 64*256;
  float* n2R    = zone + 96 + 2*64*256;
  float* gls    = zone + 96 + 3*64*256;
  int*   counts = (int*)(zone + 96 + 3*64*256 + 256);

  float* sx = (float*)take(48*4);   float* tx = (float*)take(48*4);
  float* se = (float*)take(128*4);  float* te = (float*)take(128*4);
  float* sn1 = (float*)take(128*4); float* tn1 = (float*)take(128*4);
  float* sn2 = (float*)take(128*4); float* tn2 = (float*)take(128*4);
  float* sgl = (float*)take(128*4); float* tgl = (float*)take(128*4);
  float* c1 = (float*)take(128*4);  float* c3 = (float*)take(128*4);
  float* invc  = (float*)take((size_t)N_*4);
  float* Wcomb = (float*)take(176*128*4);
  float* M3    = (float*)take(128*128*4);
  float* gmean = (float*)take(G_*128*4);
  float* hg    = (float*)take(G_*128*4);
  int* offs = (int*)take((N_+1)*4);
  int* cur  = (int*)take(N_*4);
  int* goff = (int*)take(257*4);
  uint16_t* Mt = (uint16_t*)take(128*128*2);
  uint16_t* AC = (uint16_t*)take((size_t)N_*256*2);
  uint16_t* Bn = (uint16_t*)take((size_t)N_*128*2);
  float* aggf  = (float*)take((size_t)N_*128*4);
  float* hn2   = (float*)take((size_t)N_*128*4);
  int2* rcs = (int2*)take((size_t)E_*8);

  // Guard: if workspace is too small, skip (clean validation failure, no fault).
  if (off > ws_size) return;

  hipMemsetAsync(zone, 0, ZONE_WORDS*4, stream);
  hipMemsetAsync(aggf, 0, (size_t)N_*128*4, stream);

  hipLaunchKernelGGL(k_xstats, dim3(252), dim3(256), 0, stream, x, xstats);
  hipLaunchKernelGGL(k_hist, dim3((E_+255)/256), dim3(256), 0, stream, ei, counts);
  hipLaunchKernelGGL(k_xfin, dim3(1), dim3(64), 0, stream, xstats, bn_g, bn_b, sx, tx);
  hipLaunchKernelGGL(k_scan, dim3(1), dim3(256), 0, stream, counts, offs, cur);
  hipLaunchKernelGGL(k_place, dim3((E_+255)/256), dim3(256), 0, stream, ei, cur, rcs);
  hipLaunchKernelGGL(k_invc, dim3((N_+255)/256), dim3(256), 0, stream, counts, invc);
  hipLaunchKernelGGL(k_wprep, dim3(217), dim3(256), 0, stream,
                     eW2, n1W1, n1W2, n2W1, n2W2, glW1, n1b2, n2b2, Mt, Wcomb, M3, c1, c3);
  hipLaunchKernelGGL(k_nodegemm, dim3((N_+31)/32), dim3(256), 0, stream,
                     x, sx, tx, eW1, n1W1, AC, Bn);
  hipLaunchKernelGGL(k_estats, dim3(1024), dim3(256), 0, stream, rcs, AC, Bn, estR);
  hipLaunchKernelGGL(k_bnfin, dim3(1), dim3(128), 0, stream, estR, 64, e_g, e_be, se, te, 1.f/(float)E_);
  hipLaunchKernelGGL(k_epass, dim3(E_/64), dim3(256), 0, stream,
                     rcs, AC, Bn, Mt, se, te, se, te, 0, n1R, aggf);
  hipLaunchKernelGGL(k_bnfin, dim3(1), dim3(128), 0, stream, n1R, 64, n1_g, n1_be, sn1, tn1, 1.f/(float)E_);
  hipLaunchKernelGGL(k_epass, dim3(E_/64), dim3(256), 0, stream,
                     rcs, AC, Bn, Mt, se, te, sn1, tn1, 1, n1R, aggf);
  hipLaunchKernelGGL(k_n2, dim3((N_+31)/32), dim3(256), 0, stream,
                     x, sx, tx, aggf, invc, Wcomb, c1, counts, hn2, n2R);
  hipLaunchKernelGGL(k_bnfin, dim3(1), dim3(128), 0, stream, n2R, 64, n2_g, n2_be, sn2, tn2, 1.f/(float)N_);
  hipLaunchKernelGGL(k_goff, dim3(1), dim3(256), 0, stream, batch, goff);
  hipLaunchKernelGGL(k_gmean, dim3(256), dim3(128), 0, stream, hn2, goff, sn2, tn2, gmean);
  hipLaunchKernelGGL(k_hg, dim3(128), dim3(256), 0, stream, gmean, M3, c3, goff, hg, gls);
  hipLaunchKernelGGL(k_bnfin, dim3(1), dim3(128), 0, stream, gls, 1, gl_g, gl_be, sgl, tgl, 1.f/(float)G_);
  hipLaunchKernelGGL(k_out, dim3(2), dim3(256), 0, stream, hg, sgl, tgl, glW2, glb2, out);
}